// Round 7
// baseline (224.033 us; speedup 1.0000x reference)
//
#include <hip/hip_runtime.h>
#include <hip/hip_bf16.h>
#include <cstdint>

// Problem: B=4, T=1024, C=1024, H=16, D=64, MAX_LEN=1024, NPOS=2047
// Pipeline (R19):
//   cvt3: x, qkv_w, proj_w fp32 -> bf16 in ws (one pass)
//   table_reduce rel_pos_emb -> (2047,16)
//   gemm_bt<0>: qkv = xb @ qwb^T + b -> scatter bf16; Q,K (B,H,T,D), V (B,H,D,T)
//   attn_mfma: flash causal, level-gridded 4-wave blocks, ILP-2 streams -> y bf16
//   gemm_bt<1>: out = y @ pwb^T + b -> fp32 d_out
//
// R17 measured: attn 71.7us, occ 20.6->28.5% but time FLAT -> occupancy NOT
// binding. Spine diagnosis: per-tile serial chain = 2 max-shfls + 16 expf +
// 2 sum-shfls + Ps ds_write->ds_read (~600-700cy LDS/cross-lane latency per
// 80cy MFMA) -> MfmaUtil 4.7%.
// R19 changes (attn only):
//  1. ILP-2: independent (mi,li,oacc,Ps) per even/odd tile stream; merged
//     once at end. Removes the only cross-tile dep -> two spines interleave.
//  2. li = per-lane partial (li*alpha + local16sum, NO shfls in loop);
//     cross-quad sum once in epilogue. Valid since mnew is quad-uniform.
//  K prefetch ping-pong, V-at-top, PV operand swap, grid: unchanged.
//
// Workspace layout (bytes):
//   xb   @ 0         : 4096x1024 bf16  (8 MB)
//   qwb  @ 8388608   : 3072x1024 bf16  (6 MB)
//   pwb  @ 14680064  : 1024x1024 bf16  (2 MB)
//   table@ 16777216  : 2047x16 f32     (128 KB)
//   qkvb @ 16908288  : (3,4,16,64K) bf16 (24 MB)
//   y    @ 42074112  : 4096x1024 bf16  (8 MB)

typedef __bf16 bf16x8 __attribute__((ext_vector_type(8)));
typedef float f32x4 __attribute__((ext_vector_type(4)));

__device__ __forceinline__ float bf2f(unsigned short u) {
    return __uint_as_float(((unsigned)u) << 16);
}
__device__ __forceinline__ unsigned short f2bf(float f) {
    __hip_bfloat16 h = __float2bfloat16(f);
    return *reinterpret_cast<unsigned short*>(&h);
}
__device__ __forceinline__ int4 cvt8(float4 a, float4 b) {
    union { unsigned short s[8]; int4 v; } u;
    u.s[0] = f2bf(a.x); u.s[1] = f2bf(a.y); u.s[2] = f2bf(a.z); u.s[3] = f2bf(a.w);
    u.s[4] = f2bf(b.x); u.s[5] = f2bf(b.y); u.s[6] = f2bf(b.z); u.s[7] = f2bf(b.w);
    return u.v;
}

// async global->LDS, 16B per lane. LDS dest must be linear base+lane*16.
__device__ __forceinline__ void gload16(const void* g, void* l) {
    __builtin_amdgcn_global_load_lds(
        reinterpret_cast<const __attribute__((address_space(1))) unsigned int*>(
            reinterpret_cast<uintptr_t>(g)),
        reinterpret_cast<__attribute__((address_space(3))) unsigned int*>(
            reinterpret_cast<uintptr_t>(l)),
        16, 0, 0);
}

// ---------------- fp32 -> bf16 one-shot convert (x, qkv_w, proj_w) ----------
__global__ __launch_bounds__(256) void cvt3(const float* __restrict__ x,
                                            const float* __restrict__ w1,
                                            const float* __restrict__ w2,
                                            unsigned short* __restrict__ ox,
                                            unsigned short* __restrict__ ow1,
                                            unsigned short* __restrict__ ow2) {
    const int i = blockIdx.x * 256 + threadIdx.x;
    const float* s; unsigned short* d; int li;
    if (i < 524288)      { s = x;  d = ox;  li = i; }
    else if (i < 917504) { s = w1; d = ow1; li = i - 524288; }
    else                 { s = w2; d = ow2; li = i - 917504; }
    const float4 a = *(const float4*)(s + (size_t)li * 8);
    const float4 b = *(const float4*)(s + (size_t)li * 8 + 4);
    *(int4*)(d + (size_t)li * 8) = cvt8(a, b);
}

// ---------------- rel_pos_emb (2047,1024) -> table (2047,16) ----------------
__global__ __launch_bounds__(256) void table_reduce(const float* __restrict__ rel,
                                                    float* __restrict__ table) {
    const int p = blockIdx.x;
    const int tid = threadIdx.x, lane = tid & 63, wave = tid >> 6;
    const float* r = rel + (size_t)p * 1024;
    float s[4];
#pragma unroll
    for (int k = 0; k < 4; ++k) s[k] = r[tid + 256 * k];
#pragma unroll
    for (int k = 0; k < 4; ++k) {
        float v = s[k];
        for (int o = 32; o; o >>= 1) v += __shfl_xor(v, o, 64);
        if (lane == 0) table[p * 16 + wave + 4 * k] = v;
    }
}

// ---------------- bf16 MFMA GEMM: C = A B^T + bias (gload_lds / m97) --------
// Unchanged from R12 (measured win: MfmaUtil 31.9%, occ 74.8%).
template <int EPI>
__global__ __launch_bounds__(512) void gemm_bt(const unsigned short* __restrict__ A,
                                               const unsigned short* __restrict__ B,
                                               const float* __restrict__ bias,
                                               unsigned short* __restrict__ outb,
                                               float* __restrict__ outf,
                                               int M, int N, int K) {
    __shared__ __attribute__((aligned(16))) unsigned short As[128 * 32];
    __shared__ __attribute__((aligned(16))) unsigned short Bs[128 * 32];
    const int bm = blockIdx.x * 128, bn = blockIdx.y * 128;
    const int tid = threadIdx.x, lane = tid & 63, wave = tid >> 6;
    const int wr = wave & 1, wc = wave >> 1;  // wc in 0..3
    const int quad = lane >> 4, lm = lane & 15;

    const int srow = tid >> 2;        // 0..127
    const int scol = (tid & 3) * 8;   // shorts
    const unsigned short* Ap = A + (size_t)(bm + srow) * K + scol;
    const unsigned short* Bp = B + (size_t)(bn + srow) * K + scol;
    unsigned short* AsW = &As[tid * 8];   // == row srow, col scol (linear)
    unsigned short* BsW = &Bs[tid * 8];

    f32x4 acc[4][2];
#pragma unroll
    for (int r = 0; r < 4; ++r)
#pragma unroll
        for (int c = 0; c < 2; ++c) acc[r][c] = (f32x4){0.f, 0.f, 0.f, 0.f};

    for (int kk = 0; kk < K; kk += 32) {
        gload16(Ap + kk, AsW);
        gload16(Bp + kk, BsW);
        __syncthreads();  // compiler emits vmcnt(0) drain before s_barrier

        bf16x8 af[4], bfr[2];
#pragma unroll
        for (int r = 0; r < 4; ++r)
            af[r] = *(const bf16x8*)(&As[(64 * wr + 16 * r + lm) * 32 + quad * 8]);
#pragma unroll
        for (int c = 0; c < 2; ++c)
            bfr[c] = *(const bf16x8*)(&Bs[(32 * wc + 16 * c + lm) * 32 + quad * 8]);
#pragma unroll
        for (int r = 0; r < 4; ++r)
#pragma unroll
            for (int c = 0; c < 2; ++c)
                acc[r][c] = __builtin_amdgcn_mfma_f32_16x16x32_bf16(af[r], bfr[c], acc[r][c], 0, 0, 0);
        __syncthreads();
    }

    // C/D layout: col = lane&15, row = (lane>>4)*4 + reg
#pragma unroll
    for (int r = 0; r < 4; ++r)
#pragma unroll
        for (int c = 0; c < 2; ++c)
#pragma unroll
            for (int i = 0; i < 4; ++i) {
                const int row = bm + 64 * wr + 16 * r + quad * 4 + i;
                const int col = bn + 32 * wc + 16 * c + lm;
                const float v = acc[r][c][i] + bias[col];
                if (EPI == 0) {
                    const int b = row >> 10, t = row & 1023;
                    const int s3 = col >> 10, rem = col & 1023;
                    const int h = rem >> 6, d = rem & 63;
                    const size_t base = (((size_t)s3 * 4 + b) * 16 + h) * 65536;
                    const size_t off = base + (s3 == 2 ? (size_t)d * 1024 + t
                                                       : (size_t)t * 64 + d);
                    outb[off] = f2bf(v);
                } else {
                    outf[(size_t)row * N + col] = v;
                }
            }
}

// ---------------- MFMA flash causal attention, S^T-softmax ----------------
// Grid (64 bh, 16 levels), block 256 = 4 waves (R17). Wave w: slice 4k+w,
// queries q = 16s+lm, exact ktiles = k+1 (uniform per block).
// R19: ILP-2 streams (even/odd tiles independent: MI/LIP/OACC/Ps per
// stream, merged at end) + per-lane li partial (no sum shfls in loop).

#define LOADK(DST, KT)                                                        \
    do {                                                                      \
        _Pragma("unroll")                                                     \
        for (int nb = 0; nb < 4; ++nb) {                                      \
            const size_t kr = (size_t)((KT) * 64 + nb * 16 + lm) * 64;        \
            DST[nb * 2]     = *(const bf16x8*)(Kg + kr + quad * 8);           \
            DST[nb * 2 + 1] = *(const bf16x8*)(Kg + kr + 32 + quad * 8);      \
        }                                                                     \
    } while (0)

// One k-tile for one stream. MI/LIP are float lvalues, OACC a f32x4[4],
// PSB an ushort[4][16][72] (per-stream Ps). LIP is a PER-LANE partial sum
// (cross-quad summed once in the epilogue; mnew is quad-uniform so scaling
// is consistent).
#define ATTN_TILE(KF, KT, MI, LIP, OACC, PSB)                                 \
    do {                                                                      \
        const int kt_ = (KT);                                                 \
        /* V for THIS tile: issue first, consume after softmax */             \
        bf16x8 vf[8];                                                         \
        _Pragma("unroll")                                                     \
        for (int nb = 0; nb < 4; ++nb) {                                      \
            const size_t vr = (size_t)(nb * 16 + lm) * 1024 + (size_t)kt_ * 64; \
            vf[nb * 2]     = *(const bf16x8*)(Vtg + vr + quad * 8);           \
            vf[nb * 2 + 1] = *(const bf16x8*)(Vtg + vr + 32 + quad * 8);      \
        }                                                                     \
        /* S^T = K Q^T (A = K rows j, B = Q rows q) */                        \
        f32x4 s[4];                                                           \
        _Pragma("unroll")                                                     \
        for (int nb = 0; nb < 4; ++nb) {                                      \
            s[nb] = (f32x4){0.f, 0.f, 0.f, 0.f};                              \
            s[nb] = __builtin_amdgcn_mfma_f32_16x16x32_bf16(KF[nb * 2], qf0, s[nb], 0, 0, 0); \
            s[nb] = __builtin_amdgcn_mfma_f32_16x16x32_bf16(KF[nb * 2 + 1], qf1, s[nb], 0, 0, 0); \
        }                                                                     \
        /* scale + rel-pos bias + causal mask (q lane-constant) */            \
        const int jb0 = kt_ * 64 + quad * 4;                                  \
        _Pragma("unroll")                                                     \
        for (int nb = 0; nb < 4; ++nb)                                        \
            _Pragma("unroll")                                                 \
            for (int i = 0; i < 4; ++i) {                                     \
                const int j = jb0 + nb * 16 + i;                              \
                const float v = fmaf(s[nb][i], 0.125f, tb[q - j + 127]);      \
                s[nb][i] = (j <= q) ? v : -1e30f;                             \
            }                                                                 \
        /* online softmax: local 16-reg max + cross-quad shfls (xor 16,32) */ \
        float mx = -1e30f;                                                    \
        _Pragma("unroll")                                                     \
        for (int nb = 0; nb < 4; ++nb)                                        \
            _Pragma("unroll")                                                 \
            for (int i = 0; i < 4; ++i) mx = fmaxf(mx, s[nb][i]);             \
        mx = fmaxf(mx, __shfl_xor(mx, 16, 64));                               \
        mx = fmaxf(mx, __shfl_xor(mx, 32, 64));                               \
        const float mnew = fmaxf(MI, mx);                                     \
        const float alpha = __expf(MI - mnew);                                \
        MI = mnew;                                                            \
        _Pragma("unroll")                                                     \
        for (int nb = 0; nb < 4; ++nb)                                        \
            _Pragma("unroll")                                                 \
            for (int i = 0; i < 4; ++i) s[nb][i] = __expf(s[nb][i] - mnew);   \
        float lsum = 0.f;                                                     \
        _Pragma("unroll")                                                     \
        for (int nb = 0; nb < 4; ++nb)                                        \
            lsum += (s[nb][0] + s[nb][1]) + (s[nb][2] + s[nb][3]);            \
        LIP = LIP * alpha + lsum;  /* per-lane partial; no shfls */           \
        /* P bounce: [q=lm][j] cross-quad redistribution (stream-private) */  \
        _Pragma("unroll")                                                     \
        for (int nb = 0; nb < 4; ++nb) {                                      \
            union { unsigned short u[4]; int2 v; } p4;                        \
            p4.u[0] = f2bf(s[nb][0]);                                         \
            p4.u[1] = f2bf(s[nb][1]);                                         \
            p4.u[2] = f2bf(s[nb][2]);                                         \
            p4.u[3] = f2bf(s[nb][3]);                                         \
            *(int2*)(&PSB[wave][lm][nb * 16 + quad * 4]) = p4.v;              \
        }                                                                     \
        /* alpha per-lane (oacc col = q = lm): no broadcast */                \
        _Pragma("unroll")                                                     \
        for (int nb = 0; nb < 4; ++nb)                                        \
            _Pragma("unroll")                                                 \
            for (int i = 0; i < 4; ++i) OACC[nb][i] *= alpha;                 \
        const bf16x8 p0 = *(const bf16x8*)(&PSB[wave][lm][quad * 8]);         \
        const bf16x8 p1 = *(const bf16x8*)(&PSB[wave][lm][32 + quad * 8]);    \
        /* O^T += V^T P^T : A = V^T rows d, B = P rows q */                   \
        _Pragma("unroll")                                                     \
        for (int nb = 0; nb < 4; ++nb) {                                      \
            OACC[nb] = __builtin_amdgcn_mfma_f32_16x16x32_bf16(vf[nb * 2], p0, OACC[nb], 0, 0, 0); \
            OACC[nb] = __builtin_amdgcn_mfma_f32_16x16x32_bf16(vf[nb * 2 + 1], p1, OACC[nb], 0, 0, 0); \
        }                                                                     \
    } while (0)

__global__ __launch_bounds__(256) void attn_mfma(const unsigned short* __restrict__ qkvb,
                                                 const float* __restrict__ table,
                                                 unsigned short* __restrict__ y) {
    const int bh = blockIdx.x, b = bh >> 4, h = bh & 15;
    const int level = 15 - blockIdx.y;      // 15..0, longest blocks first
    const int tid = threadIdx.x, lane = tid & 63, wave = tid >> 6;  // wave 0..3
    const int quad = lane >> 4, lm = lane & 15;

    __shared__ __attribute__((aligned(16))) unsigned short Ps[2][4][16][72];  // [stream][wave][q][j]
    __shared__ float tb[1152];

    const unsigned short* Qg  = qkvb + ((size_t)(b)*16 + h) * 65536;       // [t][d]
    const unsigned short* Kg  = qkvb + ((size_t)(4 + b)*16 + h) * 65536;   // [t][d]
    const unsigned short* Vtg = qkvb + ((size_t)(8 + b)*16 + h) * 65536;   // [d][t]

    // wave's slice: s = 4*level + wave; 16 queries q = 16s + lm
    const int sl = 4 * level + wave;
    const int q = 16 * sl + lm;
    const int ktiles = level + 1;           // exact causal tile count

    // Q fragment (MFMA B-operand in QK^T)
    const bf16x8 qf0 = *(const bf16x8*)(Qg + (size_t)q * 64 + quad * 8);
    const bf16x8 qf1 = *(const bf16x8*)(Qg + (size_t)q * 64 + 32 + quad * 8);

    // tb[i] = table[(896+i)*16+h]; needed i = q-j+127 in [64, 64*level+190]
    const int tbn = 64 * level + 191;
    for (int i = tid; i < tbn; i += 256) tb[i] = table[(896 + i) * 16 + h];
    __syncthreads();  // tb ready; only block-wide sync in the kernel

    f32x4 oa0[4], oa1[4];
#pragma unroll
    for (int nb = 0; nb < 4; ++nb) {
        oa0[nb] = (f32x4){0.f, 0.f, 0.f, 0.f};
        oa1[nb] = (f32x4){0.f, 0.f, 0.f, 0.f};
    }
    float mi0 = -1e30f, li0 = 0.f;  // stream 0 (even tiles)
    float mi1 = -1e30f, li1 = 0.f;  // stream 1 (odd tiles)

    bf16x8 kA[8], kB[8];
    LOADK(kA, 0);
    int kt = 0;
    for (; kt + 2 <= ktiles; kt += 2) {
        LOADK(kB, kt + 1);
        ATTN_TILE(kA, kt, mi0, li0, oa0, Ps[0]);
        if (kt + 2 < ktiles) LOADK(kA, kt + 2);
        ATTN_TILE(kB, kt + 1, mi1, li1, oa1, Ps[1]);
    }
    if (kt < ktiles) ATTN_TILE(kA, kt, mi0, li0, oa0, Ps[0]);  // odd tail

    // merge streams: m* = max; w_s = exp(m_s - m*). Empty stream 1 (level 0)
    // has mi1 = -1e30 -> w1 = 0. Then ONE cross-quad li reduction.
    const float mstar = fmaxf(mi0, mi1);
    const float w0 = __expf(mi0 - mstar), w1 = __expf(mi1 - mstar);
    float lip = li0 * w0 + li1 * w1;
    lip += __shfl_xor(lip, 16, 64);
    lip += __shfl_xor(lip, 32, 64);
    const float linv = 1.0f / lip;

    // epilogue: (oa0*w0 + oa1*w1)/li -> y. Lane q; d = nb*16+quad*4+i.
#pragma unroll
    for (int nb = 0; nb < 4; ++nb) {
        union { unsigned short u[4]; int2 v; } o4;
#pragma unroll
        for (int i = 0; i < 4; ++i)
            o4.u[i] = f2bf((oa0[nb][i] * w0 + oa1[nb][i] * w1) * linv);
        *(int2*)(y + ((size_t)(b * 1024 + q)) * 1024 + h * 64 + nb * 16 + quad * 4) = o4.v;
    }
}

extern "C" void kernel_launch(void* const* d_in, const int* in_sizes, int n_in,
                              void* d_out, int out_size, void* d_ws, size_t ws_size,
                              hipStream_t stream) {
    const float* x      = (const float*)d_in[0];
    const float* qkv_w  = (const float*)d_in[1];
    const float* qkv_b  = (const float*)d_in[2];
    const float* proj_w = (const float*)d_in[3];
    const float* proj_b = (const float*)d_in[4];
    const float* rel    = (const float*)d_in[5];
    float* out = (float*)d_out;

    char* ws = (char*)d_ws;
    unsigned short* xb   = (unsigned short*)(ws + 0);
    unsigned short* qwb  = (unsigned short*)(ws + 8388608);
    unsigned short* pwb  = (unsigned short*)(ws + 14680064);
    float* table         = (float*)(ws + 16777216);
    unsigned short* qkvb = (unsigned short*)(ws + 16908288);
    unsigned short* yb   = (unsigned short*)(ws + 42074112);

    cvt3<<<4096, 256, 0, stream>>>(x, qkv_w, proj_w, xb, qwb, pwb);
    table_reduce<<<2047, 256, 0, stream>>>(rel, table);
    gemm_bt<0><<<dim3(32, 24), 512, 0, stream>>>(xb, qwb, qkv_b, qkvb, nullptr,
                                                 4096, 3072, 1024);
    attn_mfma<<<dim3(64, 16), 256, 0, stream>>>(qkvb, table, yb);
    gemm_bt<1><<<dim3(32, 8), 512, 0, stream>>>(yb, pwb, proj_b, nullptr, out,
                                                4096, 1024, 1024);
}

// Round 8
// 197.662 us; speedup vs baseline: 1.1334x; 1.1334x over previous
//
#include <hip/hip_runtime.h>
#include <hip/hip_bf16.h>
#include <cstdint>

// Problem: B=4, T=1024, C=1024, H=16, D=64, MAX_LEN=1024, NPOS=2047
// Pipeline (R21):
//   cvt3: x, qkv_w, proj_w fp32 -> bf16 in ws (one pass)
//   table_reduce rel_pos_emb -> (2047,16)
//   gemm_bt<0>: qkv = xb @ qwb^T + b -> scatter bf16; Q,K (B,H,T,D), V (B,H,D,T)
//   attn_mfma: flash causal, 32x32-MFMA lane-local softmax -> y bf16
//   gemm_bt<1>: out = y @ pwb^T + b -> fp32 d_out
//
// R13/R17/R19 all left attn at 72-77us (119 TF): the 16x16 structure's
// softmax spine (2 max shfls + Ps LDS write->read re-layout per tile) is a
// structural floor (ERRATA #12 band). R21 ports attn to the 32x32 structure:
//   - mfma_f32_32x32x16_bf16, wave owns 32 q's; S^T = K Q^T -> col=q=lane&31
//     (ONE query per lane), row=j=(reg&3)+8*(reg>>2)+4*(lane>>5) [m74/m101].
//   - 32 j's per query live in lanes {lane, lane^32}: max = 15 fmax + 1 shfl;
//     li = per-lane partial (merged by 1 epilogue shfl; R19-verified).
//   - P->PV re-layout IN-REGISTER: 8 packs + 4 shfl_xor(32) + cndmask
//     (partner-exchange). Ps LDS bounce DELETED.
//   - PV operand-swapped (A=V^T rows d, B=P): O^T col=q=own lane ->
//     per-lane alpha/linv (R15-verified). Mask only on diagonal tile
//     (wave-uniform branch).
//   - Block 128 = 2 waves, grid (64 bh, 16 levels), qbase = 64*lvl+32*w,
//     exact tiles nt = 2*lvl+w+1. K ping-pong + V-at-top kept. LDS = tb only.
//
// Workspace layout (bytes):
//   xb   @ 0         : 4096x1024 bf16  (8 MB)
//   qwb  @ 8388608   : 3072x1024 bf16  (6 MB)
//   pwb  @ 14680064  : 1024x1024 bf16  (2 MB)
//   table@ 16777216  : 2047x16 f32     (128 KB)
//   qkvb @ 16908288  : (3,4,16,64K) bf16 (24 MB)
//   y    @ 42074112  : 4096x1024 bf16  (8 MB)

typedef __bf16 bf16x8 __attribute__((ext_vector_type(8)));
typedef float f32x4 __attribute__((ext_vector_type(4)));
typedef float f32x16 __attribute__((ext_vector_type(16)));

__device__ __forceinline__ float bf2f(unsigned short u) {
    return __uint_as_float(((unsigned)u) << 16);
}
__device__ __forceinline__ unsigned short f2bf(float f) {
    __hip_bfloat16 h = __float2bfloat16(f);
    return *reinterpret_cast<unsigned short*>(&h);
}
__device__ __forceinline__ unsigned pk2(float a, float b) {
    return (unsigned)f2bf(a) | ((unsigned)f2bf(b) << 16);
}
__device__ __forceinline__ int4 cvt8(float4 a, float4 b) {
    union { unsigned short s[8]; int4 v; } u;
    u.s[0] = f2bf(a.x); u.s[1] = f2bf(a.y); u.s[2] = f2bf(a.z); u.s[3] = f2bf(a.w);
    u.s[4] = f2bf(b.x); u.s[5] = f2bf(b.y); u.s[6] = f2bf(b.z); u.s[7] = f2bf(b.w);
    return u.v;
}

// async global->LDS, 16B per lane. LDS dest must be linear base+lane*16.
__device__ __forceinline__ void gload16(const void* g, void* l) {
    __builtin_amdgcn_global_load_lds(
        reinterpret_cast<const __attribute__((address_space(1))) unsigned int*>(
            reinterpret_cast<uintptr_t>(g)),
        reinterpret_cast<__attribute__((address_space(3))) unsigned int*>(
            reinterpret_cast<uintptr_t>(l)),
        16, 0, 0);
}

// ---------------- fp32 -> bf16 one-shot convert (x, qkv_w, proj_w) ----------
__global__ __launch_bounds__(256) void cvt3(const float* __restrict__ x,
                                            const float* __restrict__ w1,
                                            const float* __restrict__ w2,
                                            unsigned short* __restrict__ ox,
                                            unsigned short* __restrict__ ow1,
                                            unsigned short* __restrict__ ow2) {
    const int i = blockIdx.x * 256 + threadIdx.x;
    const float* s; unsigned short* d; int li;
    if (i < 524288)      { s = x;  d = ox;  li = i; }
    else if (i < 917504) { s = w1; d = ow1; li = i - 524288; }
    else                 { s = w2; d = ow2; li = i - 917504; }
    const float4 a = *(const float4*)(s + (size_t)li * 8);
    const float4 b = *(const float4*)(s + (size_t)li * 8 + 4);
    *(int4*)(d + (size_t)li * 8) = cvt8(a, b);
}

// ---------------- rel_pos_emb (2047,1024) -> table (2047,16) ----------------
__global__ __launch_bounds__(256) void table_reduce(const float* __restrict__ rel,
                                                    float* __restrict__ table) {
    const int p = blockIdx.x;
    const int tid = threadIdx.x, lane = tid & 63, wave = tid >> 6;
    const float* r = rel + (size_t)p * 1024;
    float s[4];
#pragma unroll
    for (int k = 0; k < 4; ++k) s[k] = r[tid + 256 * k];
#pragma unroll
    for (int k = 0; k < 4; ++k) {
        float v = s[k];
        for (int o = 32; o; o >>= 1) v += __shfl_xor(v, o, 64);
        if (lane == 0) table[p * 16 + wave + 4 * k] = v;
    }
}

// ---------------- bf16 MFMA GEMM: C = A B^T + bias (gload_lds / m97) --------
// Unchanged from R12 (measured win: MfmaUtil 31.9%, occ 74.8%).
template <int EPI>
__global__ __launch_bounds__(512) void gemm_bt(const unsigned short* __restrict__ A,
                                               const unsigned short* __restrict__ B,
                                               const float* __restrict__ bias,
                                               unsigned short* __restrict__ outb,
                                               float* __restrict__ outf,
                                               int M, int N, int K) {
    __shared__ __attribute__((aligned(16))) unsigned short As[128 * 32];
    __shared__ __attribute__((aligned(16))) unsigned short Bs[128 * 32];
    const int bm = blockIdx.x * 128, bn = blockIdx.y * 128;
    const int tid = threadIdx.x, lane = tid & 63, wave = tid >> 6;
    const int wr = wave & 1, wc = wave >> 1;  // wc in 0..3
    const int quad = lane >> 4, lm = lane & 15;

    const int srow = tid >> 2;        // 0..127
    const int scol = (tid & 3) * 8;   // shorts
    const unsigned short* Ap = A + (size_t)(bm + srow) * K + scol;
    const unsigned short* Bp = B + (size_t)(bn + srow) * K + scol;
    unsigned short* AsW = &As[tid * 8];   // == row srow, col scol (linear)
    unsigned short* BsW = &Bs[tid * 8];

    f32x4 acc[4][2];
#pragma unroll
    for (int r = 0; r < 4; ++r)
#pragma unroll
        for (int c = 0; c < 2; ++c) acc[r][c] = (f32x4){0.f, 0.f, 0.f, 0.f};

    for (int kk = 0; kk < K; kk += 32) {
        gload16(Ap + kk, AsW);
        gload16(Bp + kk, BsW);
        __syncthreads();  // compiler emits vmcnt(0) drain before s_barrier

        bf16x8 af[4], bfr[2];
#pragma unroll
        for (int r = 0; r < 4; ++r)
            af[r] = *(const bf16x8*)(&As[(64 * wr + 16 * r + lm) * 32 + quad * 8]);
#pragma unroll
        for (int c = 0; c < 2; ++c)
            bfr[c] = *(const bf16x8*)(&Bs[(32 * wc + 16 * c + lm) * 32 + quad * 8]);
#pragma unroll
        for (int r = 0; r < 4; ++r)
#pragma unroll
            for (int c = 0; c < 2; ++c)
                acc[r][c] = __builtin_amdgcn_mfma_f32_16x16x32_bf16(af[r], bfr[c], acc[r][c], 0, 0, 0);
        __syncthreads();
    }

    // C/D layout: col = lane&15, row = (lane>>4)*4 + reg
#pragma unroll
    for (int r = 0; r < 4; ++r)
#pragma unroll
        for (int c = 0; c < 2; ++c)
#pragma unroll
            for (int i = 0; i < 4; ++i) {
                const int row = bm + 64 * wr + 16 * r + quad * 4 + i;
                const int col = bn + 32 * wc + 16 * c + lm;
                const float v = acc[r][c][i] + bias[col];
                if (EPI == 0) {
                    const int b = row >> 10, t = row & 1023;
                    const int s3 = col >> 10, rem = col & 1023;
                    const int h = rem >> 6, d = rem & 63;
                    const size_t base = (((size_t)s3 * 4 + b) * 16 + h) * 65536;
                    const size_t off = base + (s3 == 2 ? (size_t)d * 1024 + t
                                                       : (size_t)t * 64 + d);
                    outb[off] = f2bf(v);
                } else {
                    outf[(size_t)row * N + col] = v;
                }
            }
}

// ---------------- MFMA flash causal attention, 32x32 lane-local softmax ----
// K fragment for 32-j tile KT: lane reads K row (KT*32 + l5), d-chunks
// t*16 + hi*8 (t=0..3). 4 x b128.
#define LOADK(DST, KT)                                                        \
    do {                                                                      \
        const unsigned short* kr_ = Kg + (size_t)((KT) * 32 + l5) * 64 + hi8; \
        DST[0] = *(const bf16x8*)(kr_);                                       \
        DST[1] = *(const bf16x8*)(kr_ + 16);                                  \
        DST[2] = *(const bf16x8*)(kr_ + 32);                                  \
        DST[3] = *(const bf16x8*)(kr_ + 48);                                  \
    } while (0)

#define ATTN_TILE(KF, KT)                                                     \
    do {                                                                      \
        const int kt_ = (KT);                                                 \
        const int jb = kt_ * 32;                                              \
        /* V for THIS tile (issue first): A-frag V^T[d=dh*32+l5][j=jb+jr*16+hi8+e] */ \
        const unsigned short* vb_ = Vtg + (size_t)l5 * 1024 + jb + hi8;       \
        const bf16x8 vf00 = *(const bf16x8*)(vb_);                            \
        const bf16x8 vf01 = *(const bf16x8*)(vb_ + 16);                       \
        const bf16x8 vf10 = *(const bf16x8*)(vb_ + 32768);                    \
        const bf16x8 vf11 = *(const bf16x8*)(vb_ + 32768 + 16);               \
        /* S^T = K Q^T over d: 4 MFMAs 32x32x16 */                            \
        f32x16 s = {0.f};                                                     \
        _Pragma("unroll")                                                     \
        for (int t = 0; t < 4; ++t)                                           \
            s = __builtin_amdgcn_mfma_f32_32x32x16_bf16(KF[t], qf[t], s, 0, 0, 0); \
        /* scale + rel-pos bias; p[reg] for j = jb + (reg&3)+8*(reg>>2)+4*hi */ \
        float p[16];                                                          \
        _Pragma("unroll")                                                     \
        for (int reg = 0; reg < 16; ++reg) {                                  \
            const int j = jb + (reg & 3) + 8 * (reg >> 2) + 4 * hi;           \
            p[reg] = fmaf(s[reg], 0.125f, tb[q - j + 127]);                   \
        }                                                                     \
        if (jb + 31 > qbase) {  /* diagonal tile only (wave-uniform) */       \
            _Pragma("unroll")                                                 \
            for (int reg = 0; reg < 16; ++reg) {                              \
                const int j = jb + (reg & 3) + 8 * (reg >> 2) + 4 * hi;       \
                p[reg] = (j <= q) ? p[reg] : -1e30f;                          \
            }                                                                 \
        }                                                                     \
        /* lane-local max (16) + partner (1 shfl) */                          \
        float mx = p[0];                                                      \
        _Pragma("unroll")                                                     \
        for (int reg = 1; reg < 16; ++reg) mx = fmaxf(mx, p[reg]);            \
        mx = fmaxf(mx, __shfl_xor(mx, 32, 64));                               \
        const float mnew = fmaxf(mi, mx);                                     \
        const float alpha = __expf(mi - mnew);                                \
        mi = mnew;                                                            \
        float lsum = 0.f;                                                     \
        _Pragma("unroll")                                                     \
        for (int reg = 0; reg < 16; ++reg) {                                  \
            p[reg] = __expf(p[reg] - mnew);                                   \
            lsum += p[reg];                                                   \
        }                                                                     \
        li = li * alpha + lsum;  /* per-lane partial; 1 shfl in epilogue */   \
        /* in-register P re-layout for PV B-frag (partner exchange) */        \
        const unsigned P0 = pk2(p[0], p[1]),   P1 = pk2(p[2], p[3]);          \
        const unsigned P2 = pk2(p[4], p[5]),   P3 = pk2(p[6], p[7]);          \
        const unsigned P4 = pk2(p[8], p[9]),   P5 = pk2(p[10], p[11]);        \
        const unsigned P6 = pk2(p[12], p[13]), P7 = pk2(p[14], p[15]);        \
        const unsigned R0 = __shfl_xor(hi ? P0 : P2, 32, 64);                 \
        const unsigned R1 = __shfl_xor(hi ? P1 : P3, 32, 64);                 \
        const unsigned R2 = __shfl_xor(hi ? P4 : P6, 32, 64);                 \
        const unsigned R3 = __shfl_xor(hi ? P5 : P7, 32, 64);                 \
        union { unsigned w[4]; bf16x8 v; } bq0, bq1;                          \
        bq0.w[0] = hi ? R0 : P0;  bq0.w[1] = hi ? R1 : P1;                    \
        bq0.w[2] = hi ? P2 : R0;  bq0.w[3] = hi ? P3 : R1;                    \
        bq1.w[0] = hi ? R2 : P4;  bq1.w[1] = hi ? R3 : P5;                    \
        bq1.w[2] = hi ? P6 : R2;  bq1.w[3] = hi ? P7 : R3;                    \
        /* alpha per-lane (O^T col = q = own lane) */                         \
        _Pragma("unroll")                                                     \
        for (int reg = 0; reg < 16; ++reg) {                                  \
            oa0[reg] *= alpha;                                                \
            oa1[reg] *= alpha;                                                \
        }                                                                     \
        /* O^T += V^T P : 4 MFMAs (2 d-halves x 2 j-ranges) */                \
        oa0 = __builtin_amdgcn_mfma_f32_32x32x16_bf16(vf00, bq0.v, oa0, 0, 0, 0); \
        oa0 = __builtin_amdgcn_mfma_f32_32x32x16_bf16(vf01, bq1.v, oa0, 0, 0, 0); \
        oa1 = __builtin_amdgcn_mfma_f32_32x32x16_bf16(vf10, bq0.v, oa1, 0, 0, 0); \
        oa1 = __builtin_amdgcn_mfma_f32_32x32x16_bf16(vf11, bq1.v, oa1, 0, 0, 0); \
    } while (0)

__global__ __launch_bounds__(128) void attn_mfma(const unsigned short* __restrict__ qkvb,
                                                 const float* __restrict__ table,
                                                 unsigned short* __restrict__ y) {
    const int bh = blockIdx.x, b = bh >> 4, h = bh & 15;
    const int level = 15 - blockIdx.y;      // 15..0, longest blocks first
    const int tid = threadIdx.x, lane = tid & 63, wave = tid >> 6;  // wave 0..1
    const int l5 = lane & 31, hi = lane >> 5, hi8 = hi * 8;

    __shared__ float tb[1152];

    const unsigned short* Qg  = qkvb + ((size_t)(b)*16 + h) * 65536;       // [t][d]
    const unsigned short* Kg  = qkvb + ((size_t)(4 + b)*16 + h) * 65536;   // [t][d]
    const unsigned short* Vtg = qkvb + ((size_t)(8 + b)*16 + h) * 65536;   // [d][t]

    const int qbase = 64 * level + 32 * wave;
    const int q = qbase + l5;               // ONE query per lane
    const int nt = 2 * level + wave + 1;    // exact causal 32-j tile count

    // Q fragment (MFMA B-operand): B[col=q][k = t*16 + hi*8 + e]
    bf16x8 qf[4];
    {
        const unsigned short* qr = Qg + (size_t)q * 64 + hi8;
#pragma unroll
        for (int t = 0; t < 4; ++t) qf[t] = *(const bf16x8*)(qr + t * 16);
    }

    // tb[i] = table[(896+i)*16+h]; needed i = q-j+127 in [96, 64*level+190]
    const int tbn = 64 * level + 191;
    for (int i = tid; i < tbn; i += 128) tb[i] = table[(896 + i) * 16 + h];
    __syncthreads();  // tb ready; only block-wide sync in the kernel

    f32x16 oa0 = {0.f}, oa1 = {0.f};  // O^T d-halves: row d, col q (own lane)
    float mi = -1e30f, li = 0.f;

    bf16x8 kA[4], kB[4];
    LOADK(kA, 0);
    int kt = 0;
    for (; kt + 2 <= nt; kt += 2) {
        LOADK(kB, kt + 1);
        ATTN_TILE(kA, kt);
        if (kt + 2 < nt) LOADK(kA, kt + 2);
        ATTN_TILE(kB, kt + 1);
    }
    if (kt < nt) ATTN_TILE(kA, kt);  // odd-nt tail (kA preloaded)

    // epilogue: li = own + partner halves (1 shfl); O^T/li -> y.
    li += __shfl_xor(li, 32, 64);
    const float linv = 1.0f / li;
    // lane's d = dh*32 + 8*g + 4*hi + (0..3)  (reg = 4g..4g+3 consecutive)
    unsigned short* yq = y + ((size_t)(b * 1024 + q)) * 1024 + h * 64;
#pragma unroll
    for (int g = 0; g < 4; ++g) {
        union { unsigned short u[4]; int2 v; } o4a, o4b;
#pragma unroll
        for (int i = 0; i < 4; ++i) {
            o4a.u[i] = f2bf(oa0[4 * g + i] * linv);
            o4b.u[i] = f2bf(oa1[4 * g + i] * linv);
        }
        *(int2*)(yq + 8 * g + 4 * hi) = o4a.v;
        *(int2*)(yq + 32 + 8 * g + 4 * hi) = o4b.v;
    }
}

extern "C" void kernel_launch(void* const* d_in, const int* in_sizes, int n_in,
                              void* d_out, int out_size, void* d_ws, size_t ws_size,
                              hipStream_t stream) {
    const float* x      = (const float*)d_in[0];
    const float* qkv_w  = (const float*)d_in[1];
    const float* qkv_b  = (const float*)d_in[2];
    const float* proj_w = (const float*)d_in[3];
    const float* proj_b = (const float*)d_in[4];
    const float* rel    = (const float*)d_in[5];
    float* out = (float*)d_out;

    char* ws = (char*)d_ws;
    unsigned short* xb   = (unsigned short*)(ws + 0);
    unsigned short* qwb  = (unsigned short*)(ws + 8388608);
    unsigned short* pwb  = (unsigned short*)(ws + 14680064);
    float* table         = (float*)(ws + 16777216);
    unsigned short* qkvb = (unsigned short*)(ws + 16908288);
    unsigned short* yb   = (unsigned short*)(ws + 42074112);

    cvt3<<<4096, 256, 0, stream>>>(x, qkv_w, proj_w, xb, qwb, pwb);
    table_reduce<<<2047, 256, 0, stream>>>(rel, table);
    gemm_bt<0><<<dim3(32, 24), 512, 0, stream>>>(xb, qwb, qkv_b, qkvb, nullptr,
                                                 4096, 3072, 1024);
    attn_mfma<<<dim3(64, 16), 128, 0, stream>>>(qkvb, table, yb);
    gemm_bt<1><<<dim3(32, 8), 512, 0, stream>>>(yb, pwb, proj_b, nullptr, out,
                                                4096, 1024, 1024);
}

// Round 9
// 193.412 us; speedup vs baseline: 1.1583x; 1.0220x over previous
//
#include <hip/hip_runtime.h>
#include <hip/hip_bf16.h>
#include <cstdint>

// Problem: B=4, T=1024, C=1024, H=16, D=64, MAX_LEN=1024, NPOS=2047
// Pipeline (R23):
//   cvt3: x, qkv_w, proj_w fp32 -> bf16 in ws (one pass)
//   table_reduce rel_pos_emb -> (2047,16)
//   gemm_bt<0>: qkv = xb @ qwb^T + b -> scatter bf16; Q,K (B,H,T,D), V (B,H,D,T)
//   attn_mfma: flash causal, 32x32 lane-local softmax, KVBLK=64 + defer-max
//   gemm_bt<1>: out = y @ pwb^T + b -> fp32 d_out
//
// R21 measured: attn 47.0us (was 77.2), MfmaUtil 6.8%, VALU 30%, occ 12%
// (grid-capped 2 waves/SIMD), VGPR 100, bank-conflicts 0. 32x32 structure
// CONFIRMED. Residual: per-tile softmax spine ~3300cy residence vs ~800cy
// issue -> spine count is the lever.
// R23 changes (attn only):
//  1. KVBLK=64: joint softmax over 2 subtiles (m214 rung, +27% there).
//     One max-reduce + one alpha + one oacc-rescale per 64 j. QK and PV
//     MFMAs run as 2 independent chains (free MFMA ILP).
//  2. T13 defer-max THR=8: skip mnew/alpha/rescale when
//     __all(mx <= mi+8) (wave-uniform branch). exp(p-mi) <= e^8 -- safe.
//  K pair-prefetch moved inside the joint tile (after QK, K-frags dead);
//  V-at-top, PV operand swap, grid (64 bh, 16 levels) x 128thr unchanged.
//
// Workspace layout (bytes):
//   xb   @ 0         : 4096x1024 bf16  (8 MB)
//   qwb  @ 8388608   : 3072x1024 bf16  (6 MB)
//   pwb  @ 14680064  : 1024x1024 bf16  (2 MB)
//   table@ 16777216  : 2047x16 f32     (128 KB)
//   qkvb @ 16908288  : (3,4,16,64K) bf16 (24 MB)
//   y    @ 42074112  : 4096x1024 bf16  (8 MB)

typedef __bf16 bf16x8 __attribute__((ext_vector_type(8)));
typedef float f32x4 __attribute__((ext_vector_type(4)));
typedef float f32x16 __attribute__((ext_vector_type(16)));

__device__ __forceinline__ float bf2f(unsigned short u) {
    return __uint_as_float(((unsigned)u) << 16);
}
__device__ __forceinline__ unsigned short f2bf(float f) {
    __hip_bfloat16 h = __float2bfloat16(f);
    return *reinterpret_cast<unsigned short*>(&h);
}
__device__ __forceinline__ unsigned pk2(float a, float b) {
    return (unsigned)f2bf(a) | ((unsigned)f2bf(b) << 16);
}
__device__ __forceinline__ int4 cvt8(float4 a, float4 b) {
    union { unsigned short s[8]; int4 v; } u;
    u.s[0] = f2bf(a.x); u.s[1] = f2bf(a.y); u.s[2] = f2bf(a.z); u.s[3] = f2bf(a.w);
    u.s[4] = f2bf(b.x); u.s[5] = f2bf(b.y); u.s[6] = f2bf(b.z); u.s[7] = f2bf(b.w);
    return u.v;
}

// async global->LDS, 16B per lane. LDS dest must be linear base+lane*16.
__device__ __forceinline__ void gload16(const void* g, void* l) {
    __builtin_amdgcn_global_load_lds(
        reinterpret_cast<const __attribute__((address_space(1))) unsigned int*>(
            reinterpret_cast<uintptr_t>(g)),
        reinterpret_cast<__attribute__((address_space(3))) unsigned int*>(
            reinterpret_cast<uintptr_t>(l)),
        16, 0, 0);
}

// ---------------- fp32 -> bf16 one-shot convert (x, qkv_w, proj_w) ----------
__global__ __launch_bounds__(256) void cvt3(const float* __restrict__ x,
                                            const float* __restrict__ w1,
                                            const float* __restrict__ w2,
                                            unsigned short* __restrict__ ox,
                                            unsigned short* __restrict__ ow1,
                                            unsigned short* __restrict__ ow2) {
    const int i = blockIdx.x * 256 + threadIdx.x;
    const float* s; unsigned short* d; int li;
    if (i < 524288)      { s = x;  d = ox;  li = i; }
    else if (i < 917504) { s = w1; d = ow1; li = i - 524288; }
    else                 { s = w2; d = ow2; li = i - 917504; }
    const float4 a = *(const float4*)(s + (size_t)li * 8);
    const float4 b = *(const float4*)(s + (size_t)li * 8 + 4);
    *(int4*)(d + (size_t)li * 8) = cvt8(a, b);
}

// ---------------- rel_pos_emb (2047,1024) -> table (2047,16) ----------------
__global__ __launch_bounds__(256) void table_reduce(const float* __restrict__ rel,
                                                    float* __restrict__ table) {
    const int p = blockIdx.x;
    const int tid = threadIdx.x, lane = tid & 63, wave = tid >> 6;
    const float* r = rel + (size_t)p * 1024;
    float s[4];
#pragma unroll
    for (int k = 0; k < 4; ++k) s[k] = r[tid + 256 * k];
#pragma unroll
    for (int k = 0; k < 4; ++k) {
        float v = s[k];
        for (int o = 32; o; o >>= 1) v += __shfl_xor(v, o, 64);
        if (lane == 0) table[p * 16 + wave + 4 * k] = v;
    }
}

// ---------------- bf16 MFMA GEMM: C = A B^T + bias (gload_lds / m97) --------
// Unchanged from R12 (measured win: MfmaUtil 31.9%, occ 74.8%).
template <int EPI>
__global__ __launch_bounds__(512) void gemm_bt(const unsigned short* __restrict__ A,
                                               const unsigned short* __restrict__ B,
                                               const float* __restrict__ bias,
                                               unsigned short* __restrict__ outb,
                                               float* __restrict__ outf,
                                               int M, int N, int K) {
    __shared__ __attribute__((aligned(16))) unsigned short As[128 * 32];
    __shared__ __attribute__((aligned(16))) unsigned short Bs[128 * 32];
    const int bm = blockIdx.x * 128, bn = blockIdx.y * 128;
    const int tid = threadIdx.x, lane = tid & 63, wave = tid >> 6;
    const int wr = wave & 1, wc = wave >> 1;  // wc in 0..3
    const int quad = lane >> 4, lm = lane & 15;

    const int srow = tid >> 2;        // 0..127
    const int scol = (tid & 3) * 8;   // shorts
    const unsigned short* Ap = A + (size_t)(bm + srow) * K + scol;
    const unsigned short* Bp = B + (size_t)(bn + srow) * K + scol;
    unsigned short* AsW = &As[tid * 8];   // == row srow, col scol (linear)
    unsigned short* BsW = &Bs[tid * 8];

    f32x4 acc[4][2];
#pragma unroll
    for (int r = 0; r < 4; ++r)
#pragma unroll
        for (int c = 0; c < 2; ++c) acc[r][c] = (f32x4){0.f, 0.f, 0.f, 0.f};

    for (int kk = 0; kk < K; kk += 32) {
        gload16(Ap + kk, AsW);
        gload16(Bp + kk, BsW);
        __syncthreads();  // compiler emits vmcnt(0) drain before s_barrier

        bf16x8 af[4], bfr[2];
#pragma unroll
        for (int r = 0; r < 4; ++r)
            af[r] = *(const bf16x8*)(&As[(64 * wr + 16 * r + lm) * 32 + quad * 8]);
#pragma unroll
        for (int c = 0; c < 2; ++c)
            bfr[c] = *(const bf16x8*)(&Bs[(32 * wc + 16 * c + lm) * 32 + quad * 8]);
#pragma unroll
        for (int r = 0; r < 4; ++r)
#pragma unroll
            for (int c = 0; c < 2; ++c)
                acc[r][c] = __builtin_amdgcn_mfma_f32_16x16x32_bf16(af[r], bfr[c], acc[r][c], 0, 0, 0);
        __syncthreads();
    }

    // C/D layout: col = lane&15, row = (lane>>4)*4 + reg
#pragma unroll
    for (int r = 0; r < 4; ++r)
#pragma unroll
        for (int c = 0; c < 2; ++c)
#pragma unroll
            for (int i = 0; i < 4; ++i) {
                const int row = bm + 64 * wr + 16 * r + quad * 4 + i;
                const int col = bn + 32 * wc + 16 * c + lm;
                const float v = acc[r][c][i] + bias[col];
                if (EPI == 0) {
                    const int b = row >> 10, t = row & 1023;
                    const int s3 = col >> 10, rem = col & 1023;
                    const int h = rem >> 6, d = rem & 63;
                    const size_t base = (((size_t)s3 * 4 + b) * 16 + h) * 65536;
                    const size_t off = base + (s3 == 2 ? (size_t)d * 1024 + t
                                                       : (size_t)t * 64 + d);
                    outb[off] = f2bf(v);
                } else {
                    outf[(size_t)row * N + col] = v;
                }
            }
}

// ---------------- MFMA flash causal attention, 32x32 lane-local softmax ----
// K fragment for 32-j tile KT: lane reads K row (KT*32 + l5), d-chunks
// t*16 + hi*8 (t=0..3). 4 x b128.
#define LOADK(DST, KT)                                                        \
    do {                                                                      \
        const unsigned short* kr_ = Kg + (size_t)((KT) * 32 + l5) * 64 + hi8; \
        DST[0] = *(const bf16x8*)(kr_);                                       \
        DST[1] = *(const bf16x8*)(kr_ + 16);                                  \
        DST[2] = *(const bf16x8*)(kr_ + 32);                                  \
        DST[3] = *(const bf16x8*)(kr_ + 48);                                  \
    } while (0)

// Single 32-j tile (tail only; always-rescale path). Uses kA-style frag KF.
#define ATTN_TILE(KF, KT)                                                     \
    do {                                                                      \
        const int jb = (KT) * 32;                                             \
        const unsigned short* vb_ = Vtg + (size_t)l5 * 1024 + jb + hi8;       \
        const bf16x8 vf00 = *(const bf16x8*)(vb_);                            \
        const bf16x8 vf01 = *(const bf16x8*)(vb_ + 16);                       \
        const bf16x8 vf10 = *(const bf16x8*)(vb_ + 32768);                    \
        const bf16x8 vf11 = *(const bf16x8*)(vb_ + 32768 + 16);               \
        f32x16 s = {0.f};                                                     \
        _Pragma("unroll")                                                     \
        for (int t = 0; t < 4; ++t)                                           \
            s = __builtin_amdgcn_mfma_f32_32x32x16_bf16(KF[t], qf[t], s, 0, 0, 0); \
        float p[16];                                                          \
        _Pragma("unroll")                                                     \
        for (int reg = 0; reg < 16; ++reg) {                                  \
            const int j = jb + (reg & 3) + 8 * (reg >> 2) + 4 * hi;           \
            p[reg] = fmaf(s[reg], 0.125f, tb[q - j + 127]);                   \
        }                                                                     \
        if (jb + 31 > qbase) {                                                \
            _Pragma("unroll")                                                 \
            for (int reg = 0; reg < 16; ++reg) {                              \
                const int j = jb + (reg & 3) + 8 * (reg >> 2) + 4 * hi;       \
                p[reg] = (j <= q) ? p[reg] : -1e30f;                          \
            }                                                                 \
        }                                                                     \
        float mx = p[0];                                                      \
        _Pragma("unroll")                                                     \
        for (int reg = 1; reg < 16; ++reg) mx = fmaxf(mx, p[reg]);            \
        mx = fmaxf(mx, __shfl_xor(mx, 32, 64));                               \
        if (!__all(mx <= mi + 8.f)) {                                         \
            const float mnew = fmaxf(mi, mx);                                 \
            const float alpha = __expf(mi - mnew);                            \
            mi = mnew;                                                        \
            li *= alpha;                                                      \
            _Pragma("unroll")                                                 \
            for (int reg = 0; reg < 16; ++reg) {                              \
                oa0[reg] *= alpha;                                            \
                oa1[reg] *= alpha;                                            \
            }                                                                 \
        }                                                                     \
        float lsum = 0.f;                                                     \
        _Pragma("unroll")                                                     \
        for (int reg = 0; reg < 16; ++reg) {                                  \
            p[reg] = __expf(p[reg] - mi);                                     \
            lsum += p[reg];                                                   \
        }                                                                     \
        li += lsum;                                                           \
        const unsigned P0 = pk2(p[0], p[1]),   P1 = pk2(p[2], p[3]);          \
        const unsigned P2 = pk2(p[4], p[5]),   P3 = pk2(p[6], p[7]);          \
        const unsigned P4 = pk2(p[8], p[9]),   P5 = pk2(p[10], p[11]);        \
        const unsigned P6 = pk2(p[12], p[13]), P7 = pk2(p[14], p[15]);        \
        const unsigned R0 = __shfl_xor(hi ? P0 : P2, 32, 64);                 \
        const unsigned R1 = __shfl_xor(hi ? P1 : P3, 32, 64);                 \
        const unsigned R2 = __shfl_xor(hi ? P4 : P6, 32, 64);                 \
        const unsigned R3 = __shfl_xor(hi ? P5 : P7, 32, 64);                 \
        union { unsigned w[4]; bf16x8 v; } bq0, bq1;                          \
        bq0.w[0] = hi ? R0 : P0;  bq0.w[1] = hi ? R1 : P1;                    \
        bq0.w[2] = hi ? P2 : R0;  bq0.w[3] = hi ? P3 : R1;                    \
        bq1.w[0] = hi ? R2 : P4;  bq1.w[1] = hi ? R3 : P5;                    \
        bq1.w[2] = hi ? P6 : R2;  bq1.w[3] = hi ? P7 : R3;                    \
        oa0 = __builtin_amdgcn_mfma_f32_32x32x16_bf16(vf00, bq0.v, oa0, 0, 0, 0); \
        oa0 = __builtin_amdgcn_mfma_f32_32x32x16_bf16(vf01, bq1.v, oa0, 0, 0, 0); \
        oa1 = __builtin_amdgcn_mfma_f32_32x32x16_bf16(vf10, bq0.v, oa1, 0, 0, 0); \
        oa1 = __builtin_amdgcn_mfma_f32_32x32x16_bf16(vf11, bq1.v, oa1, 0, 0, 0); \
    } while (0)

// Pack+partner-exchange p[16] -> two PV B-frags (BQA, BQB).
#define PACKP(p, BQA, BQB)                                                    \
    do {                                                                      \
        const unsigned P0 = pk2(p[0], p[1]),   P1 = pk2(p[2], p[3]);          \
        const unsigned P2 = pk2(p[4], p[5]),   P3 = pk2(p[6], p[7]);          \
        const unsigned P4 = pk2(p[8], p[9]),   P5 = pk2(p[10], p[11]);        \
        const unsigned P6 = pk2(p[12], p[13]), P7 = pk2(p[14], p[15]);        \
        const unsigned R0 = __shfl_xor(hi ? P0 : P2, 32, 64);                 \
        const unsigned R1 = __shfl_xor(hi ? P1 : P3, 32, 64);                 \
        const unsigned R2 = __shfl_xor(hi ? P4 : P6, 32, 64);                 \
        const unsigned R3 = __shfl_xor(hi ? P5 : P7, 32, 64);                 \
        BQA.w[0] = hi ? R0 : P0;  BQA.w[1] = hi ? R1 : P1;                    \
        BQA.w[2] = hi ? P2 : R0;  BQA.w[3] = hi ? P3 : R1;                    \
        BQB.w[0] = hi ? R2 : P4;  BQB.w[1] = hi ? R3 : P5;                    \
        BQB.w[2] = hi ? P6 : R2;  BQB.w[3] = hi ? P7 : R3;                    \
    } while (0)

// Joint KVBLK=64: subtiles KT (kA) and KT+1 (kB); ONE softmax update.
// Prefetches the next K pair after QK (K frags dead there).
#define ATTN_TILE2(KT)                                                        \
    do {                                                                      \
        const int jb = (KT) * 32;                                             \
        /* V for both subtiles (issue first, consume after softmax) */        \
        const unsigned short* vb_ = Vtg + (size_t)l5 * 1024 + jb + hi8;       \
        const bf16x8 vf00 = *(const bf16x8*)(vb_);                            \
        const bf16x8 vf01 = *(const bf16x8*)(vb_ + 16);                       \
        const bf16x8 vf02 = *(const bf16x8*)(vb_ + 32);                       \
        const bf16x8 vf03 = *(const bf16x8*)(vb_ + 48);                       \
        const bf16x8 vf10 = *(const bf16x8*)(vb_ + 32768);                    \
        const bf16x8 vf11 = *(const bf16x8*)(vb_ + 32768 + 16);               \
        const bf16x8 vf12 = *(const bf16x8*)(vb_ + 32768 + 32);               \
        const bf16x8 vf13 = *(const bf16x8*)(vb_ + 32768 + 48);               \
        /* S^T for both subtiles: 2 independent MFMA chains */                \
        f32x16 s0v = {0.f}, s1v = {0.f};                                      \
        _Pragma("unroll")                                                     \
        for (int t = 0; t < 4; ++t) {                                         \
            s0v = __builtin_amdgcn_mfma_f32_32x32x16_bf16(kA[t], qf[t], s0v, 0, 0, 0); \
            s1v = __builtin_amdgcn_mfma_f32_32x32x16_bf16(kB[t], qf[t], s1v, 0, 0, 0); \
        }                                                                     \
        /* K frags dead: prefetch next pair (overlaps softmax+PV) */          \
        if ((KT) + 2 < nt) LOADK(kA, (KT) + 2);                               \
        if ((KT) + 3 < nt) LOADK(kB, (KT) + 3);                               \
        /* bias + mask per subtile */                                         \
        float p0[16], p1[16];                                                 \
        _Pragma("unroll")                                                     \
        for (int reg = 0; reg < 16; ++reg) {                                  \
            const int jo = (reg & 3) + 8 * (reg >> 2) + 4 * hi;               \
            p0[reg] = fmaf(s0v[reg], 0.125f, tb[q - jb - jo + 127]);          \
            p1[reg] = fmaf(s1v[reg], 0.125f, tb[q - jb - 32 - jo + 127]);     \
        }                                                                     \
        if (jb + 63 > qbase) {                                                \
            _Pragma("unroll")                                                 \
            for (int reg = 0; reg < 16; ++reg) {                              \
                const int jo = (reg & 3) + 8 * (reg >> 2) + 4 * hi;           \
                p0[reg] = (jb + jo <= q) ? p0[reg] : -1e30f;                  \
                p1[reg] = (jb + 32 + jo <= q) ? p1[reg] : -1e30f;             \
            }                                                                 \
        }                                                                     \
        /* joint max over 32 regs + partner (1 shfl) */                       \
        float mx = p0[0];                                                     \
        _Pragma("unroll")                                                     \
        for (int reg = 1; reg < 16; ++reg) mx = fmaxf(mx, p0[reg]);           \
        _Pragma("unroll")                                                     \
        for (int reg = 0; reg < 16; ++reg) mx = fmaxf(mx, p1[reg]);           \
        mx = fmaxf(mx, __shfl_xor(mx, 32, 64));                               \
        /* T13 defer-max: rescale only when needed (wave-uniform) */          \
        if (!__all(mx <= mi + 8.f)) {                                         \
            const float mnew = fmaxf(mi, mx);                                 \
            const float alpha = __expf(mi - mnew);                            \
            mi = mnew;                                                        \
            li *= alpha;                                                      \
            _Pragma("unroll")                                                 \
            for (int reg = 0; reg < 16; ++reg) {                              \
                oa0[reg] *= alpha;                                            \
                oa1[reg] *= alpha;                                            \
            }                                                                 \
        }                                                                     \
        float lsum = 0.f;                                                     \
        _Pragma("unroll")                                                     \
        for (int reg = 0; reg < 16; ++reg) {                                  \
            p0[reg] = __expf(p0[reg] - mi);                                   \
            p1[reg] = __expf(p1[reg] - mi);                                   \
            lsum += p0[reg] + p1[reg];                                        \
        }                                                                     \
        li += lsum;                                                           \
        /* in-register P re-layout, both subtiles */                          \
        union { unsigned w[4]; bf16x8 v; } bq00, bq01, bq10, bq11;            \
        PACKP(p0, bq00, bq01);                                                \
        PACKP(p1, bq10, bq11);                                                \
        /* O^T += V^T P : 2 independent chains of 4 */                        \
        oa0 = __builtin_amdgcn_mfma_f32_32x32x16_bf16(vf00, bq00.v, oa0, 0, 0, 0); \
        oa1 = __builtin_amdgcn_mfma_f32_32x32x16_bf16(vf10, bq00.v, oa1, 0, 0, 0); \
        oa0 = __builtin_amdgcn_mfma_f32_32x32x16_bf16(vf01, bq01.v, oa0, 0, 0, 0); \
        oa1 = __builtin_amdgcn_mfma_f32_32x32x16_bf16(vf11, bq01.v, oa1, 0, 0, 0); \
        oa0 = __builtin_amdgcn_mfma_f32_32x32x16_bf16(vf02, bq10.v, oa0, 0, 0, 0); \
        oa1 = __builtin_amdgcn_mfma_f32_32x32x16_bf16(vf12, bq10.v, oa1, 0, 0, 0); \
        oa0 = __builtin_amdgcn_mfma_f32_32x32x16_bf16(vf03, bq11.v, oa0, 0, 0, 0); \
        oa1 = __builtin_amdgcn_mfma_f32_32x32x16_bf16(vf13, bq11.v, oa1, 0, 0, 0); \
    } while (0)

__global__ __launch_bounds__(128) void attn_mfma(const unsigned short* __restrict__ qkvb,
                                                 const float* __restrict__ table,
                                                 unsigned short* __restrict__ y) {
    const int bh = blockIdx.x, b = bh >> 4, h = bh & 15;
    const int level = 15 - blockIdx.y;      // 15..0, longest blocks first
    const int tid = threadIdx.x, lane = tid & 63, wave = tid >> 6;  // wave 0..1
    const int l5 = lane & 31, hi = lane >> 5, hi8 = hi * 8;

    __shared__ float tb[1152];

    const unsigned short* Qg  = qkvb + ((size_t)(b)*16 + h) * 65536;       // [t][d]
    const unsigned short* Kg  = qkvb + ((size_t)(4 + b)*16 + h) * 65536;   // [t][d]
    const unsigned short* Vtg = qkvb + ((size_t)(8 + b)*16 + h) * 65536;   // [d][t]

    const int qbase = 64 * level + 32 * wave;
    const int q = qbase + l5;               // ONE query per lane
    const int nt = 2 * level + wave + 1;    // exact causal 32-j tile count

    // Q fragment (MFMA B-operand): B[col=q][k = t*16 + hi*8 + e]
    bf16x8 qf[4];
    {
        const unsigned short* qr = Qg + (size_t)q * 64 + hi8;
#pragma unroll
        for (int t = 0; t < 4; ++t) qf[t] = *(const bf16x8*)(qr + t * 16);
    }

    // tb[i] = table[(896+i)*16+h]; needed i = q-j+127 in [96, 64*level+190]
    const int tbn = 64 * level + 191;
    for (int i = tid; i < tbn; i += 128) tb[i] = table[(896 + i) * 16 + h];
    __syncthreads();  // tb ready; only block-wide sync in the kernel

    f32x16 oa0 = {0.f}, oa1 = {0.f};  // O^T d-halves: row d, col q (own lane)
    float mi = -1e30f, li = 0.f;

    bf16x8 kA[4], kB[4];
    LOADK(kA, 0);
    LOADK(kB, nt > 1 ? 1 : 0);
    int kt = 0;
    for (; kt + 1 < nt; kt += 2) ATTN_TILE2(kt);
    if (kt < nt) ATTN_TILE(kA, kt);  // odd-nt tail (kA prefetched by pair loop)

    // epilogue: li = own + partner halves (1 shfl); O^T/li -> y.
    li += __shfl_xor(li, 32, 64);
    const float linv = 1.0f / li;
    // lane's d = dh*32 + 8*g + 4*hi + (0..3)  (reg = 4g..4g+3 consecutive)
    unsigned short* yq = y + ((size_t)(b * 1024 + q)) * 1024 + h * 64;
#pragma unroll
    for (int g = 0; g < 4; ++g) {
        union { unsigned short u[4]; int2 v; } o4a, o4b;
#pragma unroll
        for (int i = 0; i < 4; ++i) {
            o4a.u[i] = f2bf(oa0[4 * g + i] * linv);
            o4b.u[i] = f2bf(oa1[4 * g + i] * linv);
        }
        *(int2*)(yq + 8 * g + 4 * hi) = o4a.v;
        *(int2*)(yq + 32 + 8 * g + 4 * hi) = o4b.v;
    }
}

extern "C" void kernel_launch(void* const* d_in, const int* in_sizes, int n_in,
                              void* d_out, int out_size, void* d_ws, size_t ws_size,
                              hipStream_t stream) {
    const float* x      = (const float*)d_in[0];
    const float* qkv_w  = (const float*)d_in[1];
    const float* qkv_b  = (const float*)d_in[2];
    const float* proj_w = (const float*)d_in[3];
    const float* proj_b = (const float*)d_in[4];
    const float* rel    = (const float*)d_in[5];
    float* out = (float*)d_out;

    char* ws = (char*)d_ws;
    unsigned short* xb   = (unsigned short*)(ws + 0);
    unsigned short* qwb  = (unsigned short*)(ws + 8388608);
    unsigned short* pwb  = (unsigned short*)(ws + 14680064);
    float* table         = (float*)(ws + 16777216);
    unsigned short* qkvb = (unsigned short*)(ws + 16908288);
    unsigned short* yb   = (unsigned short*)(ws + 42074112);

    cvt3<<<4096, 256, 0, stream>>>(x, qkv_w, proj_w, xb, qwb, pwb);
    table_reduce<<<2047, 256, 0, stream>>>(rel, table);
    gemm_bt<0><<<dim3(32, 24), 512, 0, stream>>>(xb, qwb, qkv_b, qkvb, nullptr,
                                                 4096, 3072, 1024);
    attn_mfma<<<dim3(64, 16), 128, 0, stream>>>(qkvb, table, yb);
    gemm_bt<1><<<dim3(32, 8), 512, 0, stream>>>(yb, pwb, proj_b, nullptr, out,
                                                4096, 1024, 1024);
}